// Round 1
// baseline (1254.597 us; speedup 1.0000x reference)
//
#include <hip/hip_runtime.h>

// ---------------------------------------------------------------------------
// LinkPredModel: 2-layer GraphSAGE (mean aggr) + dot-product link scoring.
// N=100000 nodes, D=H=128, E=3.2M edges, L=200k label pairs. All fp32.
//
// Pipeline:
//   1) build CSR by dst (count -> exclusive scan -> fill)     [int atomics only]
//   2) agg1 = mean_{src->n} x[src]                            (wave per node)
//   3) h1   = leakyrelu(agg1@W1l + b1 + x@W1r)                (wave per 4 rows)
//   4) agg2 = mean_{src->n} h1[src]
//   5) h2   = agg2@W2l + b2 + h1@W2r
//   6) out[l] = dot(h2[eli0[l]], h2[eli1[l]])                 (wave per pair)
// ---------------------------------------------------------------------------

#define D128 128

// ---------------- CSR build ----------------

__global__ void count_kernel(const int* __restrict__ dst, int* __restrict__ cnt, int E) {
    int e = blockIdx.x * blockDim.x + threadIdx.x;
    if (e < E) atomicAdd(&cnt[dst[e]], 1);
}

// chunk = 1024 elements per block (256 threads x 4)
__global__ void scan_p1(const int* __restrict__ cnt, int* __restrict__ bsums, int N) {
    __shared__ int sdata[256];
    int base = blockIdx.x * 1024 + threadIdx.x * 4;
    int s = 0;
#pragma unroll
    for (int k = 0; k < 4; ++k) {
        int i = base + k;
        if (i < N) s += cnt[i];
    }
    sdata[threadIdx.x] = s;
    __syncthreads();
    for (int off = 128; off > 0; off >>= 1) {
        if (threadIdx.x < off) sdata[threadIdx.x] += sdata[threadIdx.x + off];
        __syncthreads();
    }
    if (threadIdx.x == 0) bsums[blockIdx.x] = sdata[0];
}

// single block: exclusive scan of nb (<=256) block sums, in place
__global__ void scan_p2(int* __restrict__ bsums, int nb, int* __restrict__ rowptr, int N, int E) {
    __shared__ int sdata[256];
    int t = threadIdx.x;
    int v = (t < nb) ? bsums[t] : 0;
    sdata[t] = v;
    __syncthreads();
    for (int off = 1; off < 256; off <<= 1) {
        int add = (t >= off) ? sdata[t - off] : 0;
        __syncthreads();
        sdata[t] += add;
        __syncthreads();
    }
    if (t < nb) bsums[t] = sdata[t] - v;  // exclusive
    if (t == 0) rowptr[N] = E;
}

__global__ void scan_p3(const int* __restrict__ cnt, const int* __restrict__ bsums,
                        int* __restrict__ rowptr, int N) {
    __shared__ int sdata[256];
    int t = threadIdx.x;
    int base = blockIdx.x * 1024 + t * 4;
    int v[4];
    int s = 0;
#pragma unroll
    for (int k = 0; k < 4; ++k) {
        int i = base + k;
        v[k] = (i < N) ? cnt[i] : 0;
        s += v[k];
    }
    sdata[t] = s;
    __syncthreads();
    for (int off = 1; off < 256; off <<= 1) {
        int add = (t >= off) ? sdata[t - off] : 0;
        __syncthreads();
        sdata[t] += add;
        __syncthreads();
    }
    int run = bsums[blockIdx.x] + (sdata[t] - s);  // exclusive offset for this thread
#pragma unroll
    for (int k = 0; k < 4; ++k) {
        int i = base + k;
        if (i < N) {
            rowptr[i] = run;
            run += v[k];
        }
    }
}

__global__ void fill_kernel(const int* __restrict__ src, const int* __restrict__ dst,
                            const int* __restrict__ rowptr, int* __restrict__ cnt,
                            int* __restrict__ srcs, int E) {
    int e = blockIdx.x * blockDim.x + threadIdx.x;
    if (e < E) {
        int d = dst[e];
        int pos = rowptr[d] + atomicAdd(&cnt[d], 1);
        srcs[pos] = src[e];
    }
}

// ---------------- mean aggregation: one wave per node ----------------

__global__ void agg_kernel(const int* __restrict__ rowptr, const int* __restrict__ srcs,
                           const float* __restrict__ feat, float* __restrict__ out, int N) {
    int wave = threadIdx.x >> 6;
    int lane = threadIdx.x & 63;
    int n = blockIdx.x * 4 + wave;
    if (n >= N) return;
    int beg = rowptr[n];
    int end = rowptr[n + 1];
    const float2* f2 = (const float2*)feat;
    float2 acc0 = make_float2(0.f, 0.f);
    float2 acc1 = make_float2(0.f, 0.f);
    int j = beg;
    for (; j + 1 < end; j += 2) {
        int s0 = srcs[j];
        int s1 = srcs[j + 1];
        float2 v0 = f2[(size_t)s0 * 64 + lane];
        float2 v1 = f2[(size_t)s1 * 64 + lane];
        acc0.x += v0.x; acc0.y += v0.y;
        acc1.x += v1.x; acc1.y += v1.y;
    }
    if (j < end) {
        int s0 = srcs[j];
        float2 v0 = f2[(size_t)s0 * 64 + lane];
        acc0.x += v0.x; acc0.y += v0.y;
    }
    int deg = end - beg;
    float inv = deg > 0 ? 1.0f / (float)deg : 0.f;
    float2 r;
    r.x = (acc0.x + acc1.x) * inv;
    r.y = (acc0.y + acc1.y) * inv;
    ((float2*)out)[(size_t)n * 64 + lane] = r;
}

// ---------------- fused dual GEMV: out[n] = A[n]@Wl + b + F[n]@Wr ----------------
// one wave handles 4 rows; lane owns output cols {2*lane, 2*lane+1}.
// W row segments are loaded once per wave per k-step and reused across the 4 rows.
// A/F elements are read via wave-uniform addresses (scalar-load friendly).

template <bool LEAKY>
__global__ void mm_kernel(const float* __restrict__ A, const float* __restrict__ F,
                          const float* __restrict__ Wl, const float* __restrict__ bias,
                          const float* __restrict__ Wr, float* __restrict__ out, int N) {
    int wave = threadIdx.x >> 6;
    int lane = threadIdx.x & 63;
    int n0 = (blockIdx.x * 4 + wave) * 4;
    int n0u = __builtin_amdgcn_readfirstlane(n0);

    const float2* Wl2 = (const float2*)Wl;
    const float2* Wr2 = (const float2*)Wr;
    const float2* A2 = (const float2*)A;
    const float2* F2 = (const float2*)F;

    float2 bv = ((const float2*)bias)[lane];
    float2 acc[4];
#pragma unroll
    for (int r = 0; r < 4; ++r) acc[r] = bv;

#pragma unroll 2
    for (int dd = 0; dd < 64; ++dd) {
        float2 wl0 = Wl2[(size_t)(2 * dd) * 64 + lane];
        float2 wl1 = Wl2[(size_t)(2 * dd + 1) * 64 + lane];
        float2 wr0 = Wr2[(size_t)(2 * dd) * 64 + lane];
        float2 wr1 = Wr2[(size_t)(2 * dd + 1) * 64 + lane];
#pragma unroll
        for (int r = 0; r < 4; ++r) {
            float2 a01 = A2[(size_t)(n0u + r) * 64 + dd];  // uniform -> s_load
            float2 f01 = F2[(size_t)(n0u + r) * 64 + dd];
            acc[r].x = fmaf(a01.x, wl0.x, acc[r].x);
            acc[r].y = fmaf(a01.x, wl0.y, acc[r].y);
            acc[r].x = fmaf(a01.y, wl1.x, acc[r].x);
            acc[r].y = fmaf(a01.y, wl1.y, acc[r].y);
            acc[r].x = fmaf(f01.x, wr0.x, acc[r].x);
            acc[r].y = fmaf(f01.x, wr0.y, acc[r].y);
            acc[r].x = fmaf(f01.y, wr1.x, acc[r].x);
            acc[r].y = fmaf(f01.y, wr1.y, acc[r].y);
        }
    }

#pragma unroll
    for (int r = 0; r < 4; ++r) {
        int n = n0 + r;
        if (n < N) {
            float2 h = acc[r];
            if (LEAKY) {
                h.x = h.x >= 0.f ? h.x : 0.2f * h.x;
                h.y = h.y >= 0.f ? h.y : 0.2f * h.y;
            }
            ((float2*)out)[(size_t)n * 64 + lane] = h;
        }
    }
}

// ---------------- link scoring: one wave per pair ----------------

__global__ void score_kernel(const int* __restrict__ eli, const float* __restrict__ h,
                             float* __restrict__ out, int L) {
    int wave = threadIdx.x >> 6;
    int lane = threadIdx.x & 63;
    int l = blockIdx.x * 4 + wave;
    if (l >= L) return;
    int a = eli[l];
    int b = eli[L + l];
    const float2* h2 = (const float2*)h;
    float2 u = h2[(size_t)a * 64 + lane];
    float2 v = h2[(size_t)b * 64 + lane];
    float p = u.x * v.x + u.y * v.y;
#pragma unroll
    for (int off = 32; off > 0; off >>= 1) p += __shfl_down(p, off, 64);
    if (lane == 0) out[l] = p;
}

// ---------------- host launch ----------------

extern "C" void kernel_launch(void* const* d_in, const int* in_sizes, int n_in,
                              void* d_out, int out_size, void* d_ws, size_t ws_size,
                              hipStream_t stream) {
    const float* x   = (const float*)d_in[0];
    const int*   ei  = (const int*)d_in[1];
    const int*   eli = (const int*)d_in[2];
    const float* W1l = (const float*)d_in[3];
    const float* b1  = (const float*)d_in[4];
    const float* W1r = (const float*)d_in[5];
    const float* W2l = (const float*)d_in[6];
    const float* b2  = (const float*)d_in[7];
    const float* W2r = (const float*)d_in[8];

    const int N = in_sizes[0] / D128;
    const int E = in_sizes[1] / 2;
    const int L = in_sizes[2] / 2;
    const int* srcp = ei;
    const int* dstp = ei + E;

    char* ws = (char*)d_ws;
    size_t off = 0;
    auto alloc = [&](size_t bytes) -> void* {
        void* p = ws + off;
        off += (bytes + 255) & ~(size_t)255;
        return p;
    };
    int*   rowptr = (int*)alloc((size_t)(N + 1) * sizeof(int));
    int*   cnt    = (int*)alloc((size_t)N * sizeof(int));
    int*   bsums  = (int*)alloc(4096);
    int*   srcs   = (int*)alloc((size_t)E * sizeof(int));
    float* bufA   = (float*)alloc((size_t)N * D128 * sizeof(float));
    float* bufB   = (float*)alloc((size_t)N * D128 * sizeof(float));
    float* bufC   = (float*)alloc((size_t)N * D128 * sizeof(float));
    (void)ws_size; (void)n_in; (void)out_size;

    // --- CSR build ---
    hipMemsetAsync(cnt, 0, (size_t)N * sizeof(int), stream);
    count_kernel<<<(E + 255) / 256, 256, 0, stream>>>(dstp, cnt, E);
    int nb = (N + 1023) / 1024;
    scan_p1<<<nb, 256, 0, stream>>>(cnt, bsums, N);
    scan_p2<<<1, 256, 0, stream>>>(bsums, nb, rowptr, N, E);
    scan_p3<<<nb, 256, 0, stream>>>(cnt, bsums, rowptr, N);
    hipMemsetAsync(cnt, 0, (size_t)N * sizeof(int), stream);
    fill_kernel<<<(E + 255) / 256, 256, 0, stream>>>(srcp, dstp, rowptr, cnt, srcs, E);

    // --- layer 1 ---
    agg_kernel<<<(N + 3) / 4, 256, 0, stream>>>(rowptr, srcs, x, bufA, N);
    mm_kernel<true><<<(N + 15) / 16, 256, 0, stream>>>(bufA, x, W1l, b1, W1r, bufB, N);

    // --- layer 2 ---
    agg_kernel<<<(N + 3) / 4, 256, 0, stream>>>(rowptr, srcs, bufB, bufA, N);
    mm_kernel<false><<<(N + 15) / 16, 256, 0, stream>>>(bufA, bufB, W2l, b2, W2r, bufC, N);

    // --- scoring ---
    score_kernel<<<(L + 3) / 4, 256, 0, stream>>>(eli, bufC, (float*)d_out, L);
}

// Round 2
// 833.008 us; speedup vs baseline: 1.5061x; 1.5061x over previous
//
#include <hip/hip_runtime.h>

// ---------------------------------------------------------------------------
// LinkPredModel: 2-layer GraphSAGE (mean aggr) + dot-product link scoring.
// N=100000 nodes, D=H=128, E=3.2M edges, L=200k label pairs.
// Round 2: bf16 feature tables (half gather traffic) + MFMA bf16 GEMMs.
//
// Pipeline:
//   0) cast x -> bf16; repack [Wl;Wr] (K=256 x N=128) into MFMA B-frag layout
//   1) build CSR by dst (count -> exclusive scan -> fill)     [int atomics only]
//   2) agg1 = mean_{src->n} xb[src]                 (bf16 gather, fp32 acc)
//   3) h1   = leakyrelu([agg1|xb] @ [W1l;W1r] + b1) (MFMA 16x16x32 bf16)
//   4) agg2 = mean_{src->n} h1[src]
//   5) h2   = [agg2|h1] @ [W2l;W2r] + b2
//   6) out[l] = dot(h2[eli0[l]], h2[eli1[l]])       (bf16 gather, fp32 dot)
// ---------------------------------------------------------------------------

#define D128 128

typedef __bf16 bf16x8 __attribute__((ext_vector_type(8)));
typedef float  f32x4  __attribute__((ext_vector_type(4)));

__device__ inline unsigned short f2bf(float f) {
    unsigned u = __float_as_uint(f);
    u = u + 0x7FFF + ((u >> 16) & 1);   // round-to-nearest-even
    return (unsigned short)(u >> 16);
}
__device__ inline float bf2f(unsigned short s) {
    return __uint_as_float(((unsigned)s) << 16);
}

// ---------------- fp32 -> bf16 cast (4 elems/thread) ----------------

__global__ void cast_kernel(const float* __restrict__ in, unsigned short* __restrict__ out,
                            int n4) {
    int i = blockIdx.x * blockDim.x + threadIdx.x;
    if (i >= n4) return;
    float4 v = ((const float4*)in)[i];
    ushort4 o;
    o.x = f2bf(v.x); o.y = f2bf(v.y); o.z = f2bf(v.z); o.w = f2bf(v.w);
    ((ushort4*)out)[i] = o;
}

// ---------------- weight repack into MFMA B-fragment layout ----------------
// packed[layer][kc][nt][lane][j] = W[k][col], k = kc*32 + (lane>>4)*8 + j,
// col = nt*16 + (lane&15); k<128 -> Wl, else Wr.  32768 bf16 per layer.

__global__ void repack_kernel(const float* __restrict__ W1l, const float* __restrict__ W1r,
                              const float* __restrict__ W2l, const float* __restrict__ W2r,
                              unsigned short* __restrict__ packed) {
    int tid = blockIdx.x * blockDim.x + threadIdx.x;  // [0, 65536)
    int layer = tid >> 15;
    int r = tid & 32767;
    int j    = r & 7;
    int lane = (r >> 3) & 63;
    int nt   = (r >> 9) & 7;
    int kc   = (r >> 12) & 7;
    int k   = kc * 32 + ((lane >> 4) << 3) + j;
    int col = nt * 16 + (lane & 15);
    const float* Wl = layer ? W2l : W1l;
    const float* Wr = layer ? W2r : W1r;
    float v = (k < 128) ? Wl[k * 128 + col] : Wr[(k - 128) * 128 + col];
    packed[tid] = f2bf(v);
}

// ---------------- CSR build ----------------

__global__ void count_kernel(const int* __restrict__ dst, int* __restrict__ cnt, int E) {
    int e = blockIdx.x * blockDim.x + threadIdx.x;
    if (e < E) atomicAdd(&cnt[dst[e]], 1);
}

__global__ void scan_p1(const int* __restrict__ cnt, int* __restrict__ bsums, int N) {
    __shared__ int sdata[256];
    int base = blockIdx.x * 1024 + threadIdx.x * 4;
    int s = 0;
#pragma unroll
    for (int k = 0; k < 4; ++k) {
        int i = base + k;
        if (i < N) s += cnt[i];
    }
    sdata[threadIdx.x] = s;
    __syncthreads();
    for (int off = 128; off > 0; off >>= 1) {
        if (threadIdx.x < off) sdata[threadIdx.x] += sdata[threadIdx.x + off];
        __syncthreads();
    }
    if (threadIdx.x == 0) bsums[blockIdx.x] = sdata[0];
}

__global__ void scan_p2(int* __restrict__ bsums, int nb, int* __restrict__ rowptr, int N, int E) {
    __shared__ int sdata[256];
    int t = threadIdx.x;
    int v = (t < nb) ? bsums[t] : 0;
    sdata[t] = v;
    __syncthreads();
    for (int off = 1; off < 256; off <<= 1) {
        int add = (t >= off) ? sdata[t - off] : 0;
        __syncthreads();
        sdata[t] += add;
        __syncthreads();
    }
    if (t < nb) bsums[t] = sdata[t] - v;  // exclusive
    if (t == 0) rowptr[N] = E;
}

__global__ void scan_p3(const int* __restrict__ cnt, const int* __restrict__ bsums,
                        int* __restrict__ rowptr, int N) {
    __shared__ int sdata[256];
    int t = threadIdx.x;
    int base = blockIdx.x * 1024 + t * 4;
    int v[4];
    int s = 0;
#pragma unroll
    for (int k = 0; k < 4; ++k) {
        int i = base + k;
        v[k] = (i < N) ? cnt[i] : 0;
        s += v[k];
    }
    sdata[t] = s;
    __syncthreads();
    for (int off = 1; off < 256; off <<= 1) {
        int add = (t >= off) ? sdata[t - off] : 0;
        __syncthreads();
        sdata[t] += add;
        __syncthreads();
    }
    int run = bsums[blockIdx.x] + (sdata[t] - s);
#pragma unroll
    for (int k = 0; k < 4; ++k) {
        int i = base + k;
        if (i < N) {
            rowptr[i] = run;
            run += v[k];
        }
    }
}

__global__ void fill_kernel(const int* __restrict__ src, const int* __restrict__ dst,
                            const int* __restrict__ rowptr, int* __restrict__ cnt,
                            int* __restrict__ srcs, int E) {
    int e = blockIdx.x * blockDim.x + threadIdx.x;
    if (e < E) {
        int d = dst[e];
        int pos = rowptr[d] + atomicAdd(&cnt[d], 1);
        srcs[pos] = src[e];
    }
}

// ---------------- mean aggregation (bf16 in/out): one wave per node ----------------

__global__ void agg_kernel(const int* __restrict__ rowptr, const int* __restrict__ srcs,
                           const unsigned short* __restrict__ feat,
                           unsigned short* __restrict__ out, int N) {
    int wave = threadIdx.x >> 6;
    int lane = threadIdx.x & 63;
    int n = blockIdx.x * 4 + wave;
    if (n >= N) return;
    int beg = rowptr[n];
    int end = rowptr[n + 1];
    const ushort2* f2 = (const ushort2*)feat;  // row stride = 64 ushort2
    float ax0 = 0.f, ay0 = 0.f, ax1 = 0.f, ay1 = 0.f;
    int j = beg;
    for (; j + 1 < end; j += 2) {
        int s0 = srcs[j];
        int s1 = srcs[j + 1];
        ushort2 v0 = f2[(size_t)s0 * 64 + lane];
        ushort2 v1 = f2[(size_t)s1 * 64 + lane];
        ax0 += bf2f(v0.x); ay0 += bf2f(v0.y);
        ax1 += bf2f(v1.x); ay1 += bf2f(v1.y);
    }
    if (j < end) {
        ushort2 v0 = f2[(size_t)srcs[j] * 64 + lane];
        ax0 += bf2f(v0.x); ay0 += bf2f(v0.y);
    }
    int deg = end - beg;
    float inv = deg > 0 ? 1.0f / (float)deg : 0.f;
    ushort2 r;
    r.x = f2bf((ax0 + ax1) * inv);
    r.y = f2bf((ay0 + ay1) * inv);
    ((ushort2*)out)[(size_t)n * 64 + lane] = r;
}

// ---------------- MFMA dual-GEMM: out = act([A|F] @ Wp + b) ----------------
// Wave handles 32 rows (2 M-tiles of 16); block = 4 waves = 128 rows.
// K = 256: kc 0..3 read A (k=kc*32+...), kc 4..7 read F.
// A-frag: lane holds A[m=lane&15][k=quad*8+j] (16B contiguous load).
// B-frag: packed layout, lane holds W[k=quad*8+j][n=lane&15].
// D: col=lane&15, row=quad*4+reg.

template <bool LEAKY>
__global__ void mm_kernel(const unsigned short* __restrict__ A,
                          const unsigned short* __restrict__ F,
                          const unsigned short* __restrict__ Wp,
                          const float* __restrict__ bias,
                          unsigned short* __restrict__ out, int N) {
    int wid = threadIdx.x >> 6;
    int lane = threadIdx.x & 63;
    int quad = lane >> 4;
    int m0 = (blockIdx.x * 4 + wid) * 32;

    // clamped A-frag row indices (constant over kc)
    int rowA0 = m0 + (lane & 15);
    int rowA1 = rowA0 + 16;
    if (rowA0 > N - 1) rowA0 = N - 1;
    if (rowA1 > N - 1) rowA1 = N - 1;

    f32x4 acc[2][8];
#pragma unroll
    for (int t = 0; t < 2; ++t)
#pragma unroll
        for (int nt = 0; nt < 8; ++nt) acc[t][nt] = (f32x4){0.f, 0.f, 0.f, 0.f};

#pragma unroll
    for (int kc = 0; kc < 8; ++kc) {
        const unsigned short* src = (kc < 4) ? (A + kc * 32) : (F + (kc - 4) * 32);
        bf16x8 af0 = *(const bf16x8*)(src + (size_t)rowA0 * D128 + quad * 8);
        bf16x8 af1 = *(const bf16x8*)(src + (size_t)rowA1 * D128 + quad * 8);
        const unsigned short* wp = Wp + ((size_t)kc * 8) * 512 + lane * 8;
#pragma unroll
        for (int nt = 0; nt < 8; ++nt) {
            bf16x8 bf = *(const bf16x8*)(wp + nt * 512);
            acc[0][nt] = __builtin_amdgcn_mfma_f32_16x16x32_bf16(af0, bf, acc[0][nt], 0, 0, 0);
            acc[1][nt] = __builtin_amdgcn_mfma_f32_16x16x32_bf16(af1, bf, acc[1][nt], 0, 0, 0);
        }
    }

#pragma unroll
    for (int nt = 0; nt < 8; ++nt) {
        int col = nt * 16 + (lane & 15);
        float bv = bias[col];
#pragma unroll
        for (int t = 0; t < 2; ++t) {
#pragma unroll
            for (int r = 0; r < 4; ++r) {
                int row = m0 + t * 16 + quad * 4 + r;
                if (row < N) {
                    float v = acc[t][nt][r] + bv;
                    if (LEAKY) v = v >= 0.f ? v : 0.2f * v;
                    out[(size_t)row * D128 + col] = f2bf(v);
                }
            }
        }
    }
}

// ---------------- link scoring: one wave per pair (bf16 gather) ----------------

__global__ void score_kernel(const int* __restrict__ eli, const unsigned short* __restrict__ h,
                             float* __restrict__ out, int L) {
    int wave = threadIdx.x >> 6;
    int lane = threadIdx.x & 63;
    int l = blockIdx.x * 4 + wave;
    if (l >= L) return;
    int a = eli[l];
    int b = eli[L + l];
    const ushort2* h2 = (const ushort2*)h;
    ushort2 u = h2[(size_t)a * 64 + lane];
    ushort2 v = h2[(size_t)b * 64 + lane];
    float p = bf2f(u.x) * bf2f(v.x) + bf2f(u.y) * bf2f(v.y);
#pragma unroll
    for (int off = 32; off > 0; off >>= 1) p += __shfl_down(p, off, 64);
    if (lane == 0) out[l] = p;
}

// ---------------- host launch ----------------

extern "C" void kernel_launch(void* const* d_in, const int* in_sizes, int n_in,
                              void* d_out, int out_size, void* d_ws, size_t ws_size,
                              hipStream_t stream) {
    const float* x   = (const float*)d_in[0];
    const int*   ei  = (const int*)d_in[1];
    const int*   eli = (const int*)d_in[2];
    const float* W1l = (const float*)d_in[3];
    const float* b1  = (const float*)d_in[4];
    const float* W1r = (const float*)d_in[5];
    const float* W2l = (const float*)d_in[6];
    const float* b2  = (const float*)d_in[7];
    const float* W2r = (const float*)d_in[8];

    const int N = in_sizes[0] / D128;
    const int E = in_sizes[1] / 2;
    const int L = in_sizes[2] / 2;
    const int* srcp = ei;
    const int* dstp = ei + E;

    char* ws = (char*)d_ws;
    size_t off = 0;
    auto alloc = [&](size_t bytes) -> void* {
        void* p = ws + off;
        off += (bytes + 255) & ~(size_t)255;
        return p;
    };
    int*   rowptr = (int*)alloc((size_t)(N + 1) * sizeof(int));
    int*   cnt    = (int*)alloc((size_t)N * sizeof(int));
    int*   bsums  = (int*)alloc(4096);
    int*   srcs   = (int*)alloc((size_t)E * sizeof(int));
    unsigned short* xb   = (unsigned short*)alloc((size_t)N * D128 * 2);
    unsigned short* aggb = (unsigned short*)alloc((size_t)N * D128 * 2);
    unsigned short* h1b  = (unsigned short*)alloc((size_t)N * D128 * 2);
    unsigned short* h2b  = (unsigned short*)alloc((size_t)N * D128 * 2);
    unsigned short* Wp   = (unsigned short*)alloc(2 * 32768 * 2);
    (void)ws_size; (void)n_in; (void)out_size;

    // --- casts + weight repack ---
    int n4 = N * D128 / 4;
    cast_kernel<<<(n4 + 255) / 256, 256, 0, stream>>>(x, xb, n4);
    repack_kernel<<<65536 / 256, 256, 0, stream>>>(W1l, W1r, W2l, W2r, Wp);

    // --- CSR build ---
    hipMemsetAsync(cnt, 0, (size_t)N * sizeof(int), stream);
    count_kernel<<<(E + 255) / 256, 256, 0, stream>>>(dstp, cnt, E);
    int nb = (N + 1023) / 1024;
    scan_p1<<<nb, 256, 0, stream>>>(cnt, bsums, N);
    scan_p2<<<1, 256, 0, stream>>>(bsums, nb, rowptr, N, E);
    scan_p3<<<nb, 256, 0, stream>>>(cnt, bsums, rowptr, N);
    hipMemsetAsync(cnt, 0, (size_t)N * sizeof(int), stream);
    fill_kernel<<<(E + 255) / 256, 256, 0, stream>>>(srcp, dstp, rowptr, cnt, srcs, E);

    // --- layer 1 ---
    agg_kernel<<<(N + 3) / 4, 256, 0, stream>>>(rowptr, srcs, xb, aggb, N);
    mm_kernel<true><<<(N + 127) / 128, 256, 0, stream>>>(aggb, xb, Wp, b1, h1b, N);

    // --- layer 2 ---
    agg_kernel<<<(N + 3) / 4, 256, 0, stream>>>(rowptr, srcs, h1b, aggb, N);
    mm_kernel<false><<<(N + 127) / 128, 256, 0, stream>>>(aggb, h1b, Wp + 32768, b2, h2b, N);

    // --- scoring ---
    score_kernel<<<(L + 3) / 4, 256, 0, stream>>>(eli, h2b, (float*)d_out, L);
}

// Round 3
// 673.456 us; speedup vs baseline: 1.8629x; 1.2369x over previous
//
#include <hip/hip_runtime.h>

// ---------------------------------------------------------------------------
// LinkPredModel: 2-layer GraphSAGE (mean aggr) + dot-product link scoring.
// N=100000 nodes, D=H=128, E=3.2M edges, L=200k label pairs.
// Round 3: replace atomic-scatter CSR build (197MB write amplification) with
// a two-level bucket counting sort; all scatters stay L2-resident.
//
// Pipeline:
//   0) cast x -> bf16; repack [Wl;Wr] (K=256 x N=128) into MFMA B-frag layout
//   1) hist: bucket counts (bucket = dst>>9, 512 nodes/bucket)
//      bucket_scan: bases; scatter: edges -> dst-bucketed (src,dst) pairs
//      bucket_fill: per-bucket LDS counting sort -> rowptr + srcs
//   2) agg1 = mean_{src->n} xb[src]                 (bf16 gather, fp32 acc)
//   3) h1   = leakyrelu([agg1|xb] @ [W1l;W1r] + b1) (MFMA 16x16x32 bf16)
//   4) agg2 = mean_{src->n} h1[src]
//   5) h2   = [agg2|h1] @ [W2l;W2r] + b2
//   6) out[l] = dot(h2[eli0[l]], h2[eli1[l]])       (bf16 gather, fp32 dot)
// ---------------------------------------------------------------------------

#define D128 128
#define BSHIFT 9          // 512 nodes per bucket
#define BNODES 512

typedef __bf16 bf16x8 __attribute__((ext_vector_type(8)));
typedef float  f32x4  __attribute__((ext_vector_type(4)));

__device__ inline unsigned short f2bf(float f) {
    unsigned u = __float_as_uint(f);
    u = u + 0x7FFF + ((u >> 16) & 1);   // round-to-nearest-even
    return (unsigned short)(u >> 16);
}
__device__ inline float bf2f(unsigned short s) {
    return __uint_as_float(((unsigned)s) << 16);
}

// ---------------- fp32 -> bf16 cast (4 elems/thread) ----------------

__global__ void cast_kernel(const float* __restrict__ in, unsigned short* __restrict__ out,
                            int n4) {
    int i = blockIdx.x * blockDim.x + threadIdx.x;
    if (i >= n4) return;
    float4 v = ((const float4*)in)[i];
    ushort4 o;
    o.x = f2bf(v.x); o.y = f2bf(v.y); o.z = f2bf(v.z); o.w = f2bf(v.w);
    ((ushort4*)out)[i] = o;
}

// ---------------- weight repack into MFMA B-fragment layout ----------------
// packed[layer][kc][nt][lane][j] = W[k][col], k = kc*32 + (lane>>4)*8 + j,
// col = nt*16 + (lane&15); k<128 -> Wl, else Wr.  32768 bf16 per layer.

__global__ void repack_kernel(const float* __restrict__ W1l, const float* __restrict__ W1r,
                              const float* __restrict__ W2l, const float* __restrict__ W2r,
                              unsigned short* __restrict__ packed) {
    int tid = blockIdx.x * blockDim.x + threadIdx.x;  // [0, 65536)
    int layer = tid >> 15;
    int r = tid & 32767;
    int j    = r & 7;
    int lane = (r >> 3) & 63;
    int nt   = (r >> 9) & 7;
    int kc   = (r >> 12) & 7;
    int k   = kc * 32 + ((lane >> 4) << 3) + j;
    int col = nt * 16 + (lane & 15);
    const float* Wl = layer ? W2l : W1l;
    const float* Wr = layer ? W2r : W1r;
    float v = (k < 128) ? Wl[k * 128 + col] : Wr[(k - 128) * 128 + col];
    packed[tid] = f2bf(v);
}

// ---------------- CSR build: two-level bucket counting sort ----------------

// Pass 1: global bucket histogram. 8192 edges/block, LDS hist + one global add.
__global__ void hist_kernel(const int* __restrict__ dst, int* __restrict__ gcnt,
                            int E, int NB) {
    __shared__ int h[256];
    int t = threadIdx.x;
    h[t] = 0;
    __syncthreads();
    int base = blockIdx.x * 8192;
#pragma unroll
    for (int k = 0; k < 32; ++k) {
        int e = base + k * 256 + t;
        if (e < E) atomicAdd(&h[dst[e] >> BSHIFT], 1);
    }
    __syncthreads();
    if (t < NB && h[t]) atomicAdd(&gcnt[t], h[t]);
}

// Pass 2: exclusive scan of bucket counts (single block).
__global__ void bucket_scan(const int* __restrict__ gcnt, int* __restrict__ bucket_base,
                            int* __restrict__ bucket_cur, int* __restrict__ rowptr,
                            int NB, int N, int E) {
    __shared__ int sc[256];
    __shared__ int orig[256];
    int t = threadIdx.x;
    int v = (t < NB) ? gcnt[t] : 0;
    orig[t] = v;
    sc[t] = v;
    __syncthreads();
    for (int off = 1; off < 256; off <<= 1) {
        int a = (t >= off) ? sc[t - off] : 0;
        __syncthreads();
        sc[t] += a;
        __syncthreads();
    }
    int ex = sc[t] - orig[t];
    if (t < NB) { bucket_base[t] = ex; bucket_cur[t] = ex; }
    if (t == 0) { bucket_base[NB] = E; rowptr[N] = E; }
}

// Pass 3: scatter edges into dst-bucketed pair array. Block locally sorts
// 1024 edges by bucket in LDS, reserves contiguous global chunks per bucket,
// then writes piecewise-contiguous runs (coalesced-ish, no 16x amplification).
__global__ void scatter_kernel(const int* __restrict__ src, const int* __restrict__ dst,
                               int* __restrict__ bucket_cur, int2* __restrict__ pairs,
                               int E, int NB) {
    __shared__ int hist[256], lscan[256], gbase[256];
    __shared__ int lsrc[1024], ldst[1024];
    int t = threadIdx.x;
    hist[t] = 0;
    __syncthreads();
    int base = blockIdx.x * 1024;
    int total = E - base; if (total > 1024) total = 1024;

    int ms[4], md[4], mb[4], mr[4];
#pragma unroll
    for (int k = 0; k < 4; ++k) {
        int i = k * 256 + t;
        int e = base + i;
        mb[k] = -1;
        if (i < total) {
            ms[k] = src[e];
            md[k] = dst[e];
            mb[k] = md[k] >> BSHIFT;
            mr[k] = atomicAdd(&hist[mb[k]], 1);
        }
    }
    __syncthreads();
    // exclusive scan of hist
    lscan[t] = hist[t];
    __syncthreads();
    for (int off = 1; off < 256; off <<= 1) {
        int a = (t >= off) ? lscan[t - off] : 0;
        __syncthreads();
        lscan[t] += a;
        __syncthreads();
    }
    lscan[t] -= hist[t];
    // reserve global space per bucket
    if (t < NB && hist[t] > 0) gbase[t] = atomicAdd(&bucket_cur[t], hist[t]);
    __syncthreads();
    // stage sorted-by-bucket into LDS
#pragma unroll
    for (int k = 0; k < 4; ++k) {
        if (mb[k] >= 0) {
            int idx = lscan[mb[k]] + mr[k];
            lsrc[idx] = ms[k];
            ldst[idx] = md[k];
        }
    }
    __syncthreads();
    // write out runs
#pragma unroll
    for (int k = 0; k < 4; ++k) {
        int i = k * 256 + t;
        if (i < total) {
            int d = ldst[i];
            int b = d >> BSHIFT;
            int pos = gbase[b] + (i - lscan[b]);
            pairs[pos] = make_int2(lsrc[i], d);
        }
    }
}

// Pass 4: one block per bucket. LDS per-node histogram + scan -> rowptr,
// then scatter src into the bucket's contiguous (L2-resident) srcs region.
__global__ void bucket_fill(const int2* __restrict__ pairs, const int* __restrict__ bucket_base,
                            int* __restrict__ rowptr, int* __restrict__ srcs, int N) {
    __shared__ int hist[BNODES], excl[BNODES], sc[BNODES];
    int b = blockIdx.x;
    int t = threadIdx.x;      // blockDim = 512
    int node0 = b << BSHIFT;
    int pbeg = bucket_base[b];
    int pend = bucket_base[b + 1];
    hist[t] = 0;
    __syncthreads();
    for (int p = pbeg + t; p < pend; p += BNODES) {
        atomicAdd(&hist[pairs[p].y - node0], 1);
    }
    __syncthreads();
    sc[t] = hist[t];
    __syncthreads();
    for (int off = 1; off < BNODES; off <<= 1) {
        int a = (t >= off) ? sc[t - off] : 0;
        __syncthreads();
        sc[t] += a;
        __syncthreads();
    }
    excl[t] = sc[t] - hist[t];
    int node = node0 + t;
    if (node < N) rowptr[node] = pbeg + excl[t];
    __syncthreads();
    hist[t] = 0;
    __syncthreads();
    for (int p = pbeg + t; p < pend; p += BNODES) {
        int2 pr = pairs[p];
        int dl = pr.y - node0;
        int c = atomicAdd(&hist[dl], 1);
        srcs[pbeg + excl[dl] + c] = pr.x;
    }
}

// ---------------- mean aggregation (bf16 in/out): one wave per node ----------------

__global__ void agg_kernel(const int* __restrict__ rowptr, const int* __restrict__ srcs,
                           const unsigned short* __restrict__ feat,
                           unsigned short* __restrict__ out, int N) {
    int wave = threadIdx.x >> 6;
    int lane = threadIdx.x & 63;
    int n = blockIdx.x * 4 + wave;
    if (n >= N) return;
    int beg = rowptr[n];
    int end = rowptr[n + 1];
    const ushort2* f2 = (const ushort2*)feat;  // row stride = 64 ushort2
    float ax0 = 0.f, ay0 = 0.f, ax1 = 0.f, ay1 = 0.f;
    int j = beg;
    for (; j + 1 < end; j += 2) {
        int s0 = srcs[j];
        int s1 = srcs[j + 1];
        ushort2 v0 = f2[(size_t)s0 * 64 + lane];
        ushort2 v1 = f2[(size_t)s1 * 64 + lane];
        ax0 += bf2f(v0.x); ay0 += bf2f(v0.y);
        ax1 += bf2f(v1.x); ay1 += bf2f(v1.y);
    }
    if (j < end) {
        ushort2 v0 = f2[(size_t)srcs[j] * 64 + lane];
        ax0 += bf2f(v0.x); ay0 += bf2f(v0.y);
    }
    int deg = end - beg;
    float inv = deg > 0 ? 1.0f / (float)deg : 0.f;
    ushort2 r;
    r.x = f2bf((ax0 + ax1) * inv);
    r.y = f2bf((ay0 + ay1) * inv);
    ((ushort2*)out)[(size_t)n * 64 + lane] = r;
}

// ---------------- MFMA dual-GEMM: out = act([A|F] @ Wp + b) ----------------

template <bool LEAKY>
__global__ void mm_kernel(const unsigned short* __restrict__ A,
                          const unsigned short* __restrict__ F,
                          const unsigned short* __restrict__ Wp,
                          const float* __restrict__ bias,
                          unsigned short* __restrict__ out, int N) {
    int wid = threadIdx.x >> 6;
    int lane = threadIdx.x & 63;
    int quad = lane >> 4;
    int m0 = (blockIdx.x * 4 + wid) * 32;

    int rowA0 = m0 + (lane & 15);
    int rowA1 = rowA0 + 16;
    if (rowA0 > N - 1) rowA0 = N - 1;
    if (rowA1 > N - 1) rowA1 = N - 1;

    f32x4 acc[2][8];
#pragma unroll
    for (int t = 0; t < 2; ++t)
#pragma unroll
        for (int nt = 0; nt < 8; ++nt) acc[t][nt] = (f32x4){0.f, 0.f, 0.f, 0.f};

#pragma unroll
    for (int kc = 0; kc < 8; ++kc) {
        const unsigned short* src = (kc < 4) ? (A + kc * 32) : (F + (kc - 4) * 32);
        bf16x8 af0 = *(const bf16x8*)(src + (size_t)rowA0 * D128 + quad * 8);
        bf16x8 af1 = *(const bf16x8*)(src + (size_t)rowA1 * D128 + quad * 8);
        const unsigned short* wp = Wp + ((size_t)kc * 8) * 512 + lane * 8;
#pragma unroll
        for (int nt = 0; nt < 8; ++nt) {
            bf16x8 bf = *(const bf16x8*)(wp + nt * 512);
            acc[0][nt] = __builtin_amdgcn_mfma_f32_16x16x32_bf16(af0, bf, acc[0][nt], 0, 0, 0);
            acc[1][nt] = __builtin_amdgcn_mfma_f32_16x16x32_bf16(af1, bf, acc[1][nt], 0, 0, 0);
        }
    }

#pragma unroll
    for (int nt = 0; nt < 8; ++nt) {
        int col = nt * 16 + (lane & 15);
        float bv = bias[col];
#pragma unroll
        for (int t = 0; t < 2; ++t) {
#pragma unroll
            for (int r = 0; r < 4; ++r) {
                int row = m0 + t * 16 + quad * 4 + r;
                if (row < N) {
                    float v = acc[t][nt][r] + bv;
                    if (LEAKY) v = v >= 0.f ? v : 0.2f * v;
                    out[(size_t)row * D128 + col] = f2bf(v);
                }
            }
        }
    }
}

// ---------------- link scoring: one wave per pair (bf16 gather) ----------------

__global__ void score_kernel(const int* __restrict__ eli, const unsigned short* __restrict__ h,
                             float* __restrict__ out, int L) {
    int wave = threadIdx.x >> 6;
    int lane = threadIdx.x & 63;
    int l = blockIdx.x * 4 + wave;
    if (l >= L) return;
    int a = eli[l];
    int b = eli[L + l];
    const ushort2* h2 = (const ushort2*)h;
    ushort2 u = h2[(size_t)a * 64 + lane];
    ushort2 v = h2[(size_t)b * 64 + lane];
    float p = bf2f(u.x) * bf2f(v.x) + bf2f(u.y) * bf2f(v.y);
#pragma unroll
    for (int off = 32; off > 0; off >>= 1) p += __shfl_down(p, off, 64);
    if (lane == 0) out[l] = p;
}

// ---------------- host launch ----------------

extern "C" void kernel_launch(void* const* d_in, const int* in_sizes, int n_in,
                              void* d_out, int out_size, void* d_ws, size_t ws_size,
                              hipStream_t stream) {
    const float* x   = (const float*)d_in[0];
    const int*   ei  = (const int*)d_in[1];
    const int*   eli = (const int*)d_in[2];
    const float* W1l = (const float*)d_in[3];
    const float* b1  = (const float*)d_in[4];
    const float* W1r = (const float*)d_in[5];
    const float* W2l = (const float*)d_in[6];
    const float* b2  = (const float*)d_in[7];
    const float* W2r = (const float*)d_in[8];

    const int N = in_sizes[0] / D128;
    const int E = in_sizes[1] / 2;
    const int L = in_sizes[2] / 2;
    const int* srcp = ei;
    const int* dstp = ei + E;
    const int NB = (N + BNODES - 1) >> BSHIFT;   // 196 for N=100000 (<=256)

    char* ws = (char*)d_ws;
    size_t off = 0;
    auto alloc = [&](size_t bytes) -> void* {
        void* p = ws + off;
        off += (bytes + 255) & ~(size_t)255;
        return p;
    };
    int*   rowptr = (int*)alloc((size_t)(N + 1) * sizeof(int));
    int*   gcnt   = (int*)alloc(256 * sizeof(int));
    int*   bbase  = (int*)alloc(257 * sizeof(int));
    int*   bcur   = (int*)alloc(256 * sizeof(int));
    int2*  pairs  = (int2*)alloc((size_t)E * sizeof(int2));
    int*   srcs   = (int*)alloc((size_t)E * sizeof(int));
    unsigned short* xb   = (unsigned short*)alloc((size_t)N * D128 * 2);
    unsigned short* aggb = (unsigned short*)alloc((size_t)N * D128 * 2);
    unsigned short* h1b  = (unsigned short*)alloc((size_t)N * D128 * 2);
    unsigned short* h2b  = (unsigned short*)alloc((size_t)N * D128 * 2);
    unsigned short* Wp   = (unsigned short*)alloc(2 * 32768 * 2);
    (void)ws_size; (void)n_in; (void)out_size;

    // --- casts + weight repack ---
    int n4 = N * D128 / 4;
    cast_kernel<<<(n4 + 255) / 256, 256, 0, stream>>>(x, xb, n4);
    repack_kernel<<<65536 / 256, 256, 0, stream>>>(W1l, W1r, W2l, W2r, Wp);

    // --- CSR build (bucket counting sort) ---
    hipMemsetAsync(gcnt, 0, 256 * sizeof(int), stream);
    hist_kernel<<<(E + 8191) / 8192, 256, 0, stream>>>(dstp, gcnt, E, NB);
    bucket_scan<<<1, 256, 0, stream>>>(gcnt, bbase, bcur, rowptr, NB, N, E);
    scatter_kernel<<<(E + 1023) / 1024, 256, 0, stream>>>(srcp, dstp, bcur, pairs, E, NB);
    bucket_fill<<<NB, BNODES, 0, stream>>>(pairs, bbase, rowptr, srcs, N);

    // --- layer 1 ---
    agg_kernel<<<(N + 3) / 4, 256, 0, stream>>>(rowptr, srcs, xb, aggb, N);
    mm_kernel<true><<<(N + 127) / 128, 256, 0, stream>>>(aggb, xb, Wp, b1, h1b, N);

    // --- layer 2 ---
    agg_kernel<<<(N + 3) / 4, 256, 0, stream>>>(rowptr, srcs, h1b, aggb, N);
    mm_kernel<false><<<(N + 127) / 128, 256, 0, stream>>>(aggb, h1b, Wp + 32768, b2, h2b, N);

    // --- scoring ---
    score_kernel<<<(L + 3) / 4, 256, 0, stream>>>(eli, h2b, (float*)d_out, L);
}

// Round 4
// 530.679 us; speedup vs baseline: 2.3641x; 1.2690x over previous
//
#include <hip/hip_runtime.h>

// ---------------------------------------------------------------------------
// LinkPredModel: 2-layer GraphSAGE (mean aggr) + dot-product link scoring.
// N=100000 nodes, D=H=128, E=3.2M edges, L=200k label pairs.
// Round 4: latency-tolerant aggregation gather — ushort4/lane (2 edges per
// load via half-waves), 8-edge unroll => 4x512B loads in flight per wave.
// ---------------------------------------------------------------------------

#define D128 128
#define BSHIFT 9          // 512 nodes per bucket
#define BNODES 512

typedef __bf16 bf16x8 __attribute__((ext_vector_type(8)));
typedef float  f32x4  __attribute__((ext_vector_type(4)));

__device__ inline unsigned short f2bf(float f) {
    unsigned u = __float_as_uint(f);
    u = u + 0x7FFF + ((u >> 16) & 1);   // round-to-nearest-even
    return (unsigned short)(u >> 16);
}
__device__ inline float bf2f(unsigned short s) {
    return __uint_as_float(((unsigned)s) << 16);
}

// ---------------- fp32 -> bf16 cast (4 elems/thread) ----------------

__global__ void cast_kernel(const float* __restrict__ in, unsigned short* __restrict__ out,
                            int n4) {
    int i = blockIdx.x * blockDim.x + threadIdx.x;
    if (i >= n4) return;
    float4 v = ((const float4*)in)[i];
    ushort4 o;
    o.x = f2bf(v.x); o.y = f2bf(v.y); o.z = f2bf(v.z); o.w = f2bf(v.w);
    ((ushort4*)out)[i] = o;
}

// ---------------- weight repack into MFMA B-fragment layout ----------------

__global__ void repack_kernel(const float* __restrict__ W1l, const float* __restrict__ W1r,
                              const float* __restrict__ W2l, const float* __restrict__ W2r,
                              unsigned short* __restrict__ packed) {
    int tid = blockIdx.x * blockDim.x + threadIdx.x;  // [0, 65536)
    int layer = tid >> 15;
    int r = tid & 32767;
    int j    = r & 7;
    int lane = (r >> 3) & 63;
    int nt   = (r >> 9) & 7;
    int kc   = (r >> 12) & 7;
    int k   = kc * 32 + ((lane >> 4) << 3) + j;
    int col = nt * 16 + (lane & 15);
    const float* Wl = layer ? W2l : W1l;
    const float* Wr = layer ? W2r : W1r;
    float v = (k < 128) ? Wl[k * 128 + col] : Wr[(k - 128) * 128 + col];
    packed[tid] = f2bf(v);
}

// ---------------- CSR build: two-level bucket counting sort ----------------

__global__ void hist_kernel(const int* __restrict__ dst, int* __restrict__ gcnt,
                            int E, int NB) {
    __shared__ int h[256];
    int t = threadIdx.x;
    h[t] = 0;
    __syncthreads();
    int base = blockIdx.x * 8192;
#pragma unroll
    for (int k = 0; k < 32; ++k) {
        int e = base + k * 256 + t;
        if (e < E) atomicAdd(&h[dst[e] >> BSHIFT], 1);
    }
    __syncthreads();
    if (t < NB && h[t]) atomicAdd(&gcnt[t], h[t]);
}

__global__ void bucket_scan(const int* __restrict__ gcnt, int* __restrict__ bucket_base,
                            int* __restrict__ bucket_cur, int* __restrict__ rowptr,
                            int NB, int N, int E) {
    __shared__ int sc[256];
    __shared__ int orig[256];
    int t = threadIdx.x;
    int v = (t < NB) ? gcnt[t] : 0;
    orig[t] = v;
    sc[t] = v;
    __syncthreads();
    for (int off = 1; off < 256; off <<= 1) {
        int a = (t >= off) ? sc[t - off] : 0;
        __syncthreads();
        sc[t] += a;
        __syncthreads();
    }
    int ex = sc[t] - orig[t];
    if (t < NB) { bucket_base[t] = ex; bucket_cur[t] = ex; }
    if (t == 0) { bucket_base[NB] = E; rowptr[N] = E; }
}

__global__ void scatter_kernel(const int* __restrict__ src, const int* __restrict__ dst,
                               int* __restrict__ bucket_cur, int2* __restrict__ pairs,
                               int E, int NB) {
    __shared__ int hist[256], lscan[256], gbase[256];
    __shared__ int lsrc[1024], ldst[1024];
    int t = threadIdx.x;
    hist[t] = 0;
    __syncthreads();
    int base = blockIdx.x * 1024;
    int total = E - base; if (total > 1024) total = 1024;

    int ms[4], md[4], mb[4], mr[4];
#pragma unroll
    for (int k = 0; k < 4; ++k) {
        int i = k * 256 + t;
        int e = base + i;
        mb[k] = -1;
        if (i < total) {
            ms[k] = src[e];
            md[k] = dst[e];
            mb[k] = md[k] >> BSHIFT;
            mr[k] = atomicAdd(&hist[mb[k]], 1);
        }
    }
    __syncthreads();
    lscan[t] = hist[t];
    __syncthreads();
    for (int off = 1; off < 256; off <<= 1) {
        int a = (t >= off) ? lscan[t - off] : 0;
        __syncthreads();
        lscan[t] += a;
        __syncthreads();
    }
    lscan[t] -= hist[t];
    if (t < NB && hist[t] > 0) gbase[t] = atomicAdd(&bucket_cur[t], hist[t]);
    __syncthreads();
#pragma unroll
    for (int k = 0; k < 4; ++k) {
        if (mb[k] >= 0) {
            int idx = lscan[mb[k]] + mr[k];
            lsrc[idx] = ms[k];
            ldst[idx] = md[k];
        }
    }
    __syncthreads();
#pragma unroll
    for (int k = 0; k < 4; ++k) {
        int i = k * 256 + t;
        if (i < total) {
            int d = ldst[i];
            int b = d >> BSHIFT;
            int pos = gbase[b] + (i - lscan[b]);
            pairs[pos] = make_int2(lsrc[i], d);
        }
    }
}

__global__ void bucket_fill(const int2* __restrict__ pairs, const int* __restrict__ bucket_base,
                            int* __restrict__ rowptr, int* __restrict__ srcs, int N) {
    __shared__ int hist[BNODES], excl[BNODES], sc[BNODES];
    int b = blockIdx.x;
    int t = threadIdx.x;      // blockDim = 512
    int node0 = b << BSHIFT;
    int pbeg = bucket_base[b];
    int pend = bucket_base[b + 1];
    hist[t] = 0;
    __syncthreads();
    for (int p = pbeg + t; p < pend; p += BNODES) {
        atomicAdd(&hist[pairs[p].y - node0], 1);
    }
    __syncthreads();
    sc[t] = hist[t];
    __syncthreads();
    for (int off = 1; off < BNODES; off <<= 1) {
        int a = (t >= off) ? sc[t - off] : 0;
        __syncthreads();
        sc[t] += a;
        __syncthreads();
    }
    excl[t] = sc[t] - hist[t];
    int node = node0 + t;
    if (node < N) rowptr[node] = pbeg + excl[t];
    __syncthreads();
    hist[t] = 0;
    __syncthreads();
    for (int p = pbeg + t; p < pend; p += BNODES) {
        int2 pr = pairs[p];
        int dl = pr.y - node0;
        int c = atomicAdd(&hist[dl], 1);
        srcs[pbeg + excl[dl] + c] = pr.x;
    }
}

// ---------------- mean aggregation: one wave per node, 2 edges/load ----------------
// lane = half*32 + hl: half-wave h covers edge slot (j + half); lane's ushort4
// covers cols 4*hl..4*hl+3. 8-edge unroll => 4 independent 512B gathers in flight.

__global__ void agg_kernel(const int* __restrict__ rowptr, const int* __restrict__ srcs,
                           const unsigned short* __restrict__ feat,
                           unsigned short* __restrict__ out, int N) {
    int wave = threadIdx.x >> 6;
    int lane = threadIdx.x & 63;
    int half = lane >> 5;
    int hl = lane & 31;
    int n = blockIdx.x * 4 + wave;
    if (n >= N) return;
    int beg = rowptr[n];
    int end = rowptr[n + 1];
    const ushort4* f4 = (const ushort4*)feat;   // row stride = 32 ushort4

    float a0=0.f,a1=0.f,a2=0.f,a3=0.f;
    float b0=0.f,b1=0.f,b2=0.f,b3=0.f;
    float c0=0.f,c1=0.f,c2=0.f,c3=0.f;
    float d0=0.f,d1=0.f,d2=0.f,d3=0.f;

    int j = beg;
    for (; j + 8 <= end; j += 8) {
        int e0 = srcs[j + 0 + half];
        int e1 = srcs[j + 2 + half];
        int e2 = srcs[j + 4 + half];
        int e3 = srcs[j + 6 + half];
        ushort4 v0 = f4[(size_t)e0 * 32 + hl];
        ushort4 v1 = f4[(size_t)e1 * 32 + hl];
        ushort4 v2 = f4[(size_t)e2 * 32 + hl];
        ushort4 v3 = f4[(size_t)e3 * 32 + hl];
        a0 += bf2f(v0.x); a1 += bf2f(v0.y); a2 += bf2f(v0.z); a3 += bf2f(v0.w);
        b0 += bf2f(v1.x); b1 += bf2f(v1.y); b2 += bf2f(v1.z); b3 += bf2f(v1.w);
        c0 += bf2f(v2.x); c1 += bf2f(v2.y); c2 += bf2f(v2.z); c3 += bf2f(v2.w);
        d0 += bf2f(v3.x); d1 += bf2f(v3.y); d2 += bf2f(v3.z); d3 += bf2f(v3.w);
    }
    for (; j + 2 <= end; j += 2) {
        int e = srcs[j + half];
        ushort4 v = f4[(size_t)e * 32 + hl];
        a0 += bf2f(v.x); a1 += bf2f(v.y); a2 += bf2f(v.z); a3 += bf2f(v.w);
    }
    if (j < end && half == 0) {
        ushort4 v = f4[(size_t)srcs[j] * 32 + hl];
        a0 += bf2f(v.x); a1 += bf2f(v.y); a2 += bf2f(v.z); a3 += bf2f(v.w);
    }

    a0 += b0 + c0 + d0;
    a1 += b1 + c1 + d1;
    a2 += b2 + c2 + d2;
    a3 += b3 + c3 + d3;
    a0 += __shfl_xor(a0, 32, 64);
    a1 += __shfl_xor(a1, 32, 64);
    a2 += __shfl_xor(a2, 32, 64);
    a3 += __shfl_xor(a3, 32, 64);

    int deg = end - beg;
    float inv = deg > 0 ? 1.0f / (float)deg : 0.f;
    if (half == 0) {
        ushort4 r;
        r.x = f2bf(a0 * inv);
        r.y = f2bf(a1 * inv);
        r.z = f2bf(a2 * inv);
        r.w = f2bf(a3 * inv);
        ((ushort4*)out)[(size_t)n * 32 + hl] = r;
    }
}

// ---------------- MFMA dual-GEMM: out = act([A|F] @ Wp + b) ----------------

template <bool LEAKY>
__global__ void mm_kernel(const unsigned short* __restrict__ A,
                          const unsigned short* __restrict__ F,
                          const unsigned short* __restrict__ Wp,
                          const float* __restrict__ bias,
                          unsigned short* __restrict__ out, int N) {
    int wid = threadIdx.x >> 6;
    int lane = threadIdx.x & 63;
    int quad = lane >> 4;
    int m0 = (blockIdx.x * 4 + wid) * 32;

    int rowA0 = m0 + (lane & 15);
    int rowA1 = rowA0 + 16;
    if (rowA0 > N - 1) rowA0 = N - 1;
    if (rowA1 > N - 1) rowA1 = N - 1;

    f32x4 acc[2][8];
#pragma unroll
    for (int t = 0; t < 2; ++t)
#pragma unroll
        for (int nt = 0; nt < 8; ++nt) acc[t][nt] = (f32x4){0.f, 0.f, 0.f, 0.f};

#pragma unroll
    for (int kc = 0; kc < 8; ++kc) {
        const unsigned short* src = (kc < 4) ? (A + kc * 32) : (F + (kc - 4) * 32);
        bf16x8 af0 = *(const bf16x8*)(src + (size_t)rowA0 * D128 + quad * 8);
        bf16x8 af1 = *(const bf16x8*)(src + (size_t)rowA1 * D128 + quad * 8);
        const unsigned short* wp = Wp + ((size_t)kc * 8) * 512 + lane * 8;
#pragma unroll
        for (int nt = 0; nt < 8; ++nt) {
            bf16x8 bf = *(const bf16x8*)(wp + nt * 512);
            acc[0][nt] = __builtin_amdgcn_mfma_f32_16x16x32_bf16(af0, bf, acc[0][nt], 0, 0, 0);
            acc[1][nt] = __builtin_amdgcn_mfma_f32_16x16x32_bf16(af1, bf, acc[1][nt], 0, 0, 0);
        }
    }

#pragma unroll
    for (int nt = 0; nt < 8; ++nt) {
        int col = nt * 16 + (lane & 15);
        float bv = bias[col];
#pragma unroll
        for (int t = 0; t < 2; ++t) {
#pragma unroll
            for (int r = 0; r < 4; ++r) {
                int row = m0 + t * 16 + quad * 4 + r;
                if (row < N) {
                    float v = acc[t][nt][r] + bv;
                    if (LEAKY) v = v >= 0.f ? v : 0.2f * v;
                    out[(size_t)row * D128 + col] = f2bf(v);
                }
            }
        }
    }
}

// ---------------- link scoring: 2 pairs per wave (4 gathers in flight) ----------------

__global__ void score_kernel(const int* __restrict__ eli, const unsigned short* __restrict__ h,
                             float* __restrict__ out, int L) {
    int wave = threadIdx.x >> 6;
    int lane = threadIdx.x & 63;
    int l0 = (blockIdx.x * 4 + wave) * 2;
    if (l0 >= L) return;
    const ushort2* h2 = (const ushort2*)h;
    int a0 = eli[l0];
    int b0 = eli[L + l0];
    bool has1 = (l0 + 1) < L;
    int a1 = has1 ? eli[l0 + 1] : a0;
    int b1 = has1 ? eli[L + l0 + 1] : b0;
    ushort2 u0 = h2[(size_t)a0 * 64 + lane];
    ushort2 v0 = h2[(size_t)b0 * 64 + lane];
    ushort2 u1 = h2[(size_t)a1 * 64 + lane];
    ushort2 v1 = h2[(size_t)b1 * 64 + lane];
    float p0 = bf2f(u0.x) * bf2f(v0.x) + bf2f(u0.y) * bf2f(v0.y);
    float p1 = bf2f(u1.x) * bf2f(v1.x) + bf2f(u1.y) * bf2f(v1.y);
#pragma unroll
    for (int off = 32; off > 0; off >>= 1) {
        p0 += __shfl_down(p0, off, 64);
        p1 += __shfl_down(p1, off, 64);
    }
    if (lane == 0) {
        out[l0] = p0;
        if (has1) out[l0 + 1] = p1;
    }
}

// ---------------- host launch ----------------

extern "C" void kernel_launch(void* const* d_in, const int* in_sizes, int n_in,
                              void* d_out, int out_size, void* d_ws, size_t ws_size,
                              hipStream_t stream) {
    const float* x   = (const float*)d_in[0];
    const int*   ei  = (const int*)d_in[1];
    const int*   eli = (const int*)d_in[2];
    const float* W1l = (const float*)d_in[3];
    const float* b1  = (const float*)d_in[4];
    const float* W1r = (const float*)d_in[5];
    const float* W2l = (const float*)d_in[6];
    const float* b2  = (const float*)d_in[7];
    const float* W2r = (const float*)d_in[8];

    const int N = in_sizes[0] / D128;
    const int E = in_sizes[1] / 2;
    const int L = in_sizes[2] / 2;
    const int* srcp = ei;
    const int* dstp = ei + E;
    const int NB = (N + BNODES - 1) >> BSHIFT;   // 196 for N=100000 (<=256)

    char* ws = (char*)d_ws;
    size_t off = 0;
    auto alloc = [&](size_t bytes) -> void* {
        void* p = ws + off;
        off += (bytes + 255) & ~(size_t)255;
        return p;
    };
    int*   rowptr = (int*)alloc((size_t)(N + 1) * sizeof(int));
    int*   gcnt   = (int*)alloc(256 * sizeof(int));
    int*   bbase  = (int*)alloc(257 * sizeof(int));
    int*   bcur   = (int*)alloc(256 * sizeof(int));
    int2*  pairs  = (int2*)alloc((size_t)E * sizeof(int2));
    int*   srcs   = (int*)alloc((size_t)E * sizeof(int));
    unsigned short* xb   = (unsigned short*)alloc((size_t)N * D128 * 2);
    unsigned short* aggb = (unsigned short*)alloc((size_t)N * D128 * 2);
    unsigned short* h1b  = (unsigned short*)alloc((size_t)N * D128 * 2);
    unsigned short* h2b  = (unsigned short*)alloc((size_t)N * D128 * 2);
    unsigned short* Wp   = (unsigned short*)alloc(2 * 32768 * 2);
    (void)ws_size; (void)n_in; (void)out_size;

    // --- casts + weight repack ---
    int n4 = N * D128 / 4;
    cast_kernel<<<(n4 + 255) / 256, 256, 0, stream>>>(x, xb, n4);
    repack_kernel<<<65536 / 256, 256, 0, stream>>>(W1l, W1r, W2l, W2r, Wp);

    // --- CSR build (bucket counting sort) ---
    hipMemsetAsync(gcnt, 0, 256 * sizeof(int), stream);
    hist_kernel<<<(E + 8191) / 8192, 256, 0, stream>>>(dstp, gcnt, E, NB);
    bucket_scan<<<1, 256, 0, stream>>>(gcnt, bbase, bcur, rowptr, NB, N, E);
    scatter_kernel<<<(E + 1023) / 1024, 256, 0, stream>>>(srcp, dstp, bcur, pairs, E, NB);
    bucket_fill<<<NB, BNODES, 0, stream>>>(pairs, bbase, rowptr, srcs, N);

    // --- layer 1 ---
    agg_kernel<<<(N + 3) / 4, 256, 0, stream>>>(rowptr, srcs, xb, aggb, N);
    mm_kernel<true><<<(N + 127) / 128, 256, 0, stream>>>(aggb, xb, Wp, b1, h1b, N);

    // --- layer 2 ---
    agg_kernel<<<(N + 3) / 4, 256, 0, stream>>>(rowptr, srcs, h1b, aggb, N);
    mm_kernel<false><<<(N + 127) / 128, 256, 0, stream>>>(aggb, h1b, Wp + 32768, b2, h2b, N);

    // --- scoring ---
    score_kernel<<<(L + 7) / 8, 256, 0, stream>>>(eli, h2b, (float*)d_out, L);
}

// Round 5
// 517.362 us; speedup vs baseline: 2.4250x; 1.0257x over previous
//
#include <hip/hip_runtime.h>

// ---------------------------------------------------------------------------
// LinkPredModel: 2-layer GraphSAGE (mean aggr) + dot-product link scoring.
// N=100000 nodes, D=H=128, E=3.2M edges, L=200k label pairs.
// Round 5: agg gather with 16B/lane (quarter-wave per row, 4 rows/load instr),
// 16-edge unroll => 4x1KB loads in flight; packed (src,dl) edge words; score
// 4-pair unroll.
// ---------------------------------------------------------------------------

#define D128 128
#define BSHIFT 9          // 512 nodes per bucket
#define BNODES 512

typedef __bf16 bf16x8 __attribute__((ext_vector_type(8)));
typedef float  f32x4  __attribute__((ext_vector_type(4)));

__device__ inline unsigned short f2bf(float f) {
    unsigned u = __float_as_uint(f);
    u = u + 0x7FFF + ((u >> 16) & 1);   // round-to-nearest-even
    return (unsigned short)(u >> 16);
}
__device__ inline float bf2f(unsigned short s) {
    return __uint_as_float(((unsigned)s) << 16);
}
__device__ inline unsigned packbf2(float lo, float hi) {
    return (unsigned)f2bf(lo) | ((unsigned)f2bf(hi) << 16);
}

// ---------------- fp32 -> bf16 cast (4 elems/thread) ----------------

__global__ void cast_kernel(const float* __restrict__ in, unsigned short* __restrict__ out,
                            int n4) {
    int i = blockIdx.x * blockDim.x + threadIdx.x;
    if (i >= n4) return;
    float4 v = ((const float4*)in)[i];
    ushort4 o;
    o.x = f2bf(v.x); o.y = f2bf(v.y); o.z = f2bf(v.z); o.w = f2bf(v.w);
    ((ushort4*)out)[i] = o;
}

// ---------------- weight repack into MFMA B-fragment layout ----------------

__global__ void repack_kernel(const float* __restrict__ W1l, const float* __restrict__ W1r,
                              const float* __restrict__ W2l, const float* __restrict__ W2r,
                              unsigned short* __restrict__ packed) {
    int tid = blockIdx.x * blockDim.x + threadIdx.x;  // [0, 65536)
    int layer = tid >> 15;
    int r = tid & 32767;
    int j    = r & 7;
    int lane = (r >> 3) & 63;
    int nt   = (r >> 9) & 7;
    int kc   = (r >> 12) & 7;
    int k   = kc * 32 + ((lane >> 4) << 3) + j;
    int col = nt * 16 + (lane & 15);
    const float* Wl = layer ? W2l : W1l;
    const float* Wr = layer ? W2r : W1r;
    float v = (k < 128) ? Wl[k * 128 + col] : Wr[(k - 128) * 128 + col];
    packed[tid] = f2bf(v);
}

// ---------------- CSR build: two-level bucket counting sort ----------------

__global__ void hist_kernel(const int* __restrict__ dst, int* __restrict__ gcnt,
                            int E, int NB) {
    __shared__ int h[256];
    int t = threadIdx.x;
    h[t] = 0;
    __syncthreads();
    int base = blockIdx.x * 8192;
#pragma unroll
    for (int k = 0; k < 32; ++k) {
        int e = base + k * 256 + t;
        if (e < E) atomicAdd(&h[dst[e] >> BSHIFT], 1);
    }
    __syncthreads();
    if (t < NB && h[t]) atomicAdd(&gcnt[t], h[t]);
}

__global__ void bucket_scan(const int* __restrict__ gcnt, int* __restrict__ bucket_base,
                            int* __restrict__ bucket_cur, int* __restrict__ rowptr,
                            int NB, int N, int E) {
    __shared__ int sc[256];
    __shared__ int orig[256];
    int t = threadIdx.x;
    int v = (t < NB) ? gcnt[t] : 0;
    orig[t] = v;
    sc[t] = v;
    __syncthreads();
    for (int off = 1; off < 256; off <<= 1) {
        int a = (t >= off) ? sc[t - off] : 0;
        __syncthreads();
        sc[t] += a;
        __syncthreads();
    }
    int ex = sc[t] - orig[t];
    if (t < NB) { bucket_base[t] = ex; bucket_cur[t] = ex; }
    if (t == 0) { bucket_base[NB] = E; rowptr[N] = E; }
}

// packed edge word: (src << 9) | (dst & 511); src < 2^17, so fits in 26 bits.
__global__ void scatter_kernel(const int* __restrict__ src, const int* __restrict__ dst,
                               int* __restrict__ bucket_cur, int* __restrict__ pairs,
                               int E, int NB) {
    __shared__ int hist[256], lscan[256], gbase[256];
    __shared__ int lsrc[1024], ldst[1024];
    int t = threadIdx.x;
    hist[t] = 0;
    __syncthreads();
    int base = blockIdx.x * 1024;
    int total = E - base; if (total > 1024) total = 1024;

    int ms[4], md[4], mb[4], mr[4];
#pragma unroll
    for (int k = 0; k < 4; ++k) {
        int i = k * 256 + t;
        int e = base + i;
        mb[k] = -1;
        if (i < total) {
            ms[k] = src[e];
            md[k] = dst[e];
            mb[k] = md[k] >> BSHIFT;
            mr[k] = atomicAdd(&hist[mb[k]], 1);
        }
    }
    __syncthreads();
    lscan[t] = hist[t];
    __syncthreads();
    for (int off = 1; off < 256; off <<= 1) {
        int a = (t >= off) ? lscan[t - off] : 0;
        __syncthreads();
        lscan[t] += a;
        __syncthreads();
    }
    lscan[t] -= hist[t];
    if (t < NB && hist[t] > 0) gbase[t] = atomicAdd(&bucket_cur[t], hist[t]);
    __syncthreads();
#pragma unroll
    for (int k = 0; k < 4; ++k) {
        if (mb[k] >= 0) {
            int idx = lscan[mb[k]] + mr[k];
            lsrc[idx] = ms[k];
            ldst[idx] = md[k];
        }
    }
    __syncthreads();
#pragma unroll
    for (int k = 0; k < 4; ++k) {
        int i = k * 256 + t;
        if (i < total) {
            int d = ldst[i];
            int b = d >> BSHIFT;
            int pos = gbase[b] + (i - lscan[b]);
            pairs[pos] = (lsrc[i] << BSHIFT) | (d & (BNODES - 1));
        }
    }
}

__global__ void bucket_fill(const int* __restrict__ pairs, const int* __restrict__ bucket_base,
                            int* __restrict__ rowptr, int* __restrict__ srcs, int N) {
    __shared__ int hist[BNODES], excl[BNODES], sc[BNODES];
    int b = blockIdx.x;
    int t = threadIdx.x;      // blockDim = 512
    int node0 = b << BSHIFT;
    int pbeg = bucket_base[b];
    int pend = bucket_base[b + 1];
    hist[t] = 0;
    __syncthreads();
    for (int p = pbeg + t; p < pend; p += BNODES) {
        atomicAdd(&hist[pairs[p] & (BNODES - 1)], 1);
    }
    __syncthreads();
    sc[t] = hist[t];
    __syncthreads();
    for (int off = 1; off < BNODES; off <<= 1) {
        int a = (t >= off) ? sc[t - off] : 0;
        __syncthreads();
        sc[t] += a;
        __syncthreads();
    }
    excl[t] = sc[t] - hist[t];
    int node = node0 + t;
    if (node < N) rowptr[node] = pbeg + excl[t];
    __syncthreads();
    hist[t] = 0;
    __syncthreads();
    for (int p = pbeg + t; p < pend; p += BNODES) {
        int w = pairs[p];
        int dl = w & (BNODES - 1);
        int c = atomicAdd(&hist[dl], 1);
        srcs[pbeg + excl[dl] + c] = ((unsigned)w) >> BSHIFT;
    }
}

// ---------------- mean aggregation: one wave per node ----------------
// 16B/lane: quarter-wave (16 lanes) covers one 256B row => one load instr
// fetches 4 edge-rows (1KB). 16-edge unroll => 4x1KB independent loads in
// flight per wave. Cross-quarter reduce at the end (2 shfl_xor per col).

__device__ inline void accum8(float* A, uint4 v) {
    A[0] += __uint_as_float(v.x << 16);
    A[1] += __uint_as_float(v.x & 0xFFFF0000u);
    A[2] += __uint_as_float(v.y << 16);
    A[3] += __uint_as_float(v.y & 0xFFFF0000u);
    A[4] += __uint_as_float(v.z << 16);
    A[5] += __uint_as_float(v.z & 0xFFFF0000u);
    A[6] += __uint_as_float(v.w << 16);
    A[7] += __uint_as_float(v.w & 0xFFFF0000u);
}

__global__ void agg_kernel(const int* __restrict__ rowptr, const int* __restrict__ srcs,
                           const unsigned short* __restrict__ feat,
                           unsigned short* __restrict__ out, int N) {
    int wave = threadIdx.x >> 6;
    int lane = threadIdx.x & 63;
    int q  = lane >> 4;    // quarter 0..3 -> edge slot within group of 4
    int ql = lane & 15;    // 16B chunk within row
    int n = blockIdx.x * 4 + wave;
    if (n >= N) return;
    int beg = rowptr[n];
    int end = rowptr[n + 1];
    const uint4* f = (const uint4*)feat;   // 16 uint4 per 256B row

    float A0[8], A1[8], A2[8], A3[8];
#pragma unroll
    for (int k = 0; k < 8; ++k) { A0[k] = 0.f; A1[k] = 0.f; A2[k] = 0.f; A3[k] = 0.f; }

    int j = beg;
    for (; j + 16 <= end; j += 16) {
        int e0 = srcs[j + q];
        int e1 = srcs[j + 4 + q];
        int e2 = srcs[j + 8 + q];
        int e3 = srcs[j + 12 + q];
        uint4 v0 = f[(size_t)e0 * 16 + ql];
        uint4 v1 = f[(size_t)e1 * 16 + ql];
        uint4 v2 = f[(size_t)e2 * 16 + ql];
        uint4 v3 = f[(size_t)e3 * 16 + ql];
        accum8(A0, v0);
        accum8(A1, v1);
        accum8(A2, v2);
        accum8(A3, v3);
    }
    for (; j + 4 <= end; j += 4) {
        int e = srcs[j + q];
        uint4 v = f[(size_t)e * 16 + ql];
        accum8(A0, v);
    }
    int rem = end - j;
    if (q < rem) {
        int e = srcs[j + q];
        uint4 v = f[(size_t)e * 16 + ql];
        accum8(A1, v);
    }

#pragma unroll
    for (int k = 0; k < 8; ++k) {
        float s = A0[k] + A1[k] + A2[k] + A3[k];
        s += __shfl_xor(s, 16, 64);
        s += __shfl_xor(s, 32, 64);
        A0[k] = s;
    }

    int deg = end - beg;
    float inv = deg > 0 ? 1.0f / (float)deg : 0.f;
    if (q == 0) {
        uint4 r;
        r.x = packbf2(A0[0] * inv, A0[1] * inv);
        r.y = packbf2(A0[2] * inv, A0[3] * inv);
        r.z = packbf2(A0[4] * inv, A0[5] * inv);
        r.w = packbf2(A0[6] * inv, A0[7] * inv);
        ((uint4*)out)[(size_t)n * 16 + ql] = r;
    }
}

// ---------------- MFMA dual-GEMM: out = act([A|F] @ Wp + b) ----------------

template <bool LEAKY>
__global__ void mm_kernel(const unsigned short* __restrict__ A,
                          const unsigned short* __restrict__ F,
                          const unsigned short* __restrict__ Wp,
                          const float* __restrict__ bias,
                          unsigned short* __restrict__ out, int N) {
    int wid = threadIdx.x >> 6;
    int lane = threadIdx.x & 63;
    int quad = lane >> 4;
    int m0 = (blockIdx.x * 4 + wid) * 32;

    int rowA0 = m0 + (lane & 15);
    int rowA1 = rowA0 + 16;
    if (rowA0 > N - 1) rowA0 = N - 1;
    if (rowA1 > N - 1) rowA1 = N - 1;

    f32x4 acc[2][8];
#pragma unroll
    for (int t = 0; t < 2; ++t)
#pragma unroll
        for (int nt = 0; nt < 8; ++nt) acc[t][nt] = (f32x4){0.f, 0.f, 0.f, 0.f};

#pragma unroll
    for (int kc = 0; kc < 8; ++kc) {
        const unsigned short* src = (kc < 4) ? (A + kc * 32) : (F + (kc - 4) * 32);
        bf16x8 af0 = *(const bf16x8*)(src + (size_t)rowA0 * D128 + quad * 8);
        bf16x8 af1 = *(const bf16x8*)(src + (size_t)rowA1 * D128 + quad * 8);
        const unsigned short* wp = Wp + ((size_t)kc * 8) * 512 + lane * 8;
#pragma unroll
        for (int nt = 0; nt < 8; ++nt) {
            bf16x8 bf = *(const bf16x8*)(wp + nt * 512);
            acc[0][nt] = __builtin_amdgcn_mfma_f32_16x16x32_bf16(af0, bf, acc[0][nt], 0, 0, 0);
            acc[1][nt] = __builtin_amdgcn_mfma_f32_16x16x32_bf16(af1, bf, acc[1][nt], 0, 0, 0);
        }
    }

#pragma unroll
    for (int nt = 0; nt < 8; ++nt) {
        int col = nt * 16 + (lane & 15);
        float bv = bias[col];
#pragma unroll
        for (int t = 0; t < 2; ++t) {
#pragma unroll
            for (int r = 0; r < 4; ++r) {
                int row = m0 + t * 16 + quad * 4 + r;
                if (row < N) {
                    float v = acc[t][nt][r] + bv;
                    if (LEAKY) v = v >= 0.f ? v : 0.2f * v;
                    out[(size_t)row * D128 + col] = f2bf(v);
                }
            }
        }
    }
}

// ---------------- link scoring: 4 pairs per wave (8 gathers in flight) ----------------

__global__ void score_kernel(const int* __restrict__ eli, const unsigned short* __restrict__ h,
                             float* __restrict__ out, int L) {
    int wave = threadIdx.x >> 6;
    int lane = threadIdx.x & 63;
    int l0 = (blockIdx.x * 4 + wave) * 4;
    if (l0 >= L) return;
    const ushort2* h2 = (const ushort2*)h;
    int a[4], b[4];
#pragma unroll
    for (int k = 0; k < 4; ++k) {
        int l = l0 + k;
        if (l > L - 1) l = L - 1;
        a[k] = eli[l];
        b[k] = eli[L + l];
    }
    float p[4];
#pragma unroll
    for (int k = 0; k < 4; ++k) {
        ushort2 u = h2[(size_t)a[k] * 64 + lane];
        ushort2 v = h2[(size_t)b[k] * 64 + lane];
        p[k] = bf2f(u.x) * bf2f(v.x) + bf2f(u.y) * bf2f(v.y);
    }
#pragma unroll
    for (int off = 32; off > 0; off >>= 1) {
#pragma unroll
        for (int k = 0; k < 4; ++k) p[k] += __shfl_down(p[k], off, 64);
    }
    if (lane == 0) {
#pragma unroll
        for (int k = 0; k < 4; ++k) {
            if (l0 + k < L) out[l0 + k] = p[k];
        }
    }
}

// ---------------- host launch ----------------

extern "C" void kernel_launch(void* const* d_in, const int* in_sizes, int n_in,
                              void* d_out, int out_size, void* d_ws, size_t ws_size,
                              hipStream_t stream) {
    const float* x   = (const float*)d_in[0];
    const int*   ei  = (const int*)d_in[1];
    const int*   eli = (const int*)d_in[2];
    const float* W1l = (const float*)d_in[3];
    const float* b1  = (const float*)d_in[4];
    const float* W1r = (const float*)d_in[5];
    const float* W2l = (const float*)d_in[6];
    const float* b2  = (const float*)d_in[7];
    const float* W2r = (const float*)d_in[8];

    const int N = in_sizes[0] / D128;
    const int E = in_sizes[1] / 2;
    const int L = in_sizes[2] / 2;
    const int* srcp = ei;
    const int* dstp = ei + E;
    const int NB = (N + BNODES - 1) >> BSHIFT;   // 196 for N=100000 (<=256)

    char* ws = (char*)d_ws;
    size_t off = 0;
    auto alloc = [&](size_t bytes) -> void* {
        void* p = ws + off;
        off += (bytes + 255) & ~(size_t)255;
        return p;
    };
    int*   rowptr = (int*)alloc((size_t)(N + 1) * sizeof(int));
    int*   gcnt   = (int*)alloc(256 * sizeof(int));
    int*   bbase  = (int*)alloc(257 * sizeof(int));
    int*   bcur   = (int*)alloc(256 * sizeof(int));
    int*   pairs  = (int*)alloc((size_t)E * sizeof(int));
    int*   srcs   = (int*)alloc((size_t)E * sizeof(int));
    unsigned short* xb   = (unsigned short*)alloc((size_t)N * D128 * 2);
    unsigned short* aggb = (unsigned short*)alloc((size_t)N * D128 * 2);
    unsigned short* h1b  = (unsigned short*)alloc((size_t)N * D128 * 2);
    unsigned short* h2b  = (unsigned short*)alloc((size_t)N * D128 * 2);
    unsigned short* Wp   = (unsigned short*)alloc(2 * 32768 * 2);
    (void)ws_size; (void)n_in; (void)out_size;

    // --- casts + weight repack ---
    int n4 = N * D128 / 4;
    cast_kernel<<<(n4 + 255) / 256, 256, 0, stream>>>(x, xb, n4);
    repack_kernel<<<65536 / 256, 256, 0, stream>>>(W1l, W1r, W2l, W2r, Wp);

    // --- CSR build (bucket counting sort) ---
    hipMemsetAsync(gcnt, 0, 256 * sizeof(int), stream);
    hist_kernel<<<(E + 8191) / 8192, 256, 0, stream>>>(dstp, gcnt, E, NB);
    bucket_scan<<<1, 256, 0, stream>>>(gcnt, bbase, bcur, rowptr, NB, N, E);
    scatter_kernel<<<(E + 1023) / 1024, 256, 0, stream>>>(srcp, dstp, bcur, pairs, E, NB);
    bucket_fill<<<NB, BNODES, 0, stream>>>(pairs, bbase, rowptr, srcs, N);

    // --- layer 1 ---
    agg_kernel<<<(N + 3) / 4, 256, 0, stream>>>(rowptr, srcs, xb, aggb, N);
    mm_kernel<true><<<(N + 127) / 128, 256, 0, stream>>>(aggb, xb, Wp, b1, h1b, N);

    // --- layer 2 ---
    agg_kernel<<<(N + 3) / 4, 256, 0, stream>>>(rowptr, srcs, h1b, aggb, N);
    mm_kernel<false><<<(N + 127) / 128, 256, 0, stream>>>(aggb, h1b, Wp + 32768, b2, h2b, N);

    // --- scoring ---
    score_kernel<<<(L + 15) / 16, 256, 0, stream>>>(eli, h2b, (float*)d_out, L);
}